// Round 8
// baseline (561.373 us; speedup 1.0000x reference)
//
#include <hip/hip_runtime.h>
#include <math.h>

#define N_NODES 200000
#define N_VAR   112000
#define N_EDGES 3200000
#define NB_SCAN 782           // ceil(200000/256)
#define PART_SZ 25000         // N_NODES / 8 partitions (one XCD each)
#define SC_CHUNK 2048         // edges scanned per scatter block
#define SC_NCHUNK 1563        // ceil(N_EDGES / SC_CHUNK)

// ---------- CSR build ----------

__global__ void k_count(const int* __restrict__ dst, int* __restrict__ deg) {
    int i = blockIdx.x * blockDim.x + threadIdx.x;   // int4 index
    if (i * 4 < N_EDGES) {
        int4 d = ((const int4*)dst)[i];
        atomicAdd(&deg[d.x], 1);
        atomicAdd(&deg[d.y], 1);
        atomicAdd(&deg[d.z], 1);
        atomicAdd(&deg[d.w], 1);
    }
}

__global__ void __launch_bounds__(256) k_scan1(const int* __restrict__ deg,
                                               int* __restrict__ rp,
                                               int* __restrict__ bsum) {
    __shared__ int tmp[256];
    int i = blockIdx.x * 256 + threadIdx.x;
    int v = (i < N_NODES) ? deg[i] : 0;
    tmp[threadIdx.x] = v;
    __syncthreads();
    for (int off = 1; off < 256; off <<= 1) {
        int t = (threadIdx.x >= off) ? tmp[threadIdx.x - off] : 0;
        __syncthreads();
        tmp[threadIdx.x] += t;
        __syncthreads();
    }
    if (i < N_NODES) rp[i] = tmp[threadIdx.x] - v;   // exclusive
    if (threadIdx.x == 255) bsum[blockIdx.x] = tmp[255];
}

__global__ void __launch_bounds__(1024) k_scan2(int* __restrict__ bsum) {
    __shared__ int tmp[1024];
    int v = (threadIdx.x < NB_SCAN) ? bsum[threadIdx.x] : 0;
    tmp[threadIdx.x] = v;
    __syncthreads();
    for (int off = 1; off < 1024; off <<= 1) {
        int t = (threadIdx.x >= off) ? tmp[threadIdx.x - off] : 0;
        __syncthreads();
        tmp[threadIdx.x] += t;
        __syncthreads();
    }
    if (threadIdx.x < NB_SCAN) bsum[threadIdx.x] = tmp[threadIdx.x] - v;
}

// finalize row_ptr, init cursor, compute dinv and xn = x*dinv
__global__ void __launch_bounds__(256) k_scan3(const int* __restrict__ deg,
                                               int* __restrict__ rp,
                                               const int* __restrict__ bsum,
                                               int* __restrict__ cursor,
                                               const float* __restrict__ x,
                                               float* __restrict__ dinv,
                                               float2* __restrict__ xn) {
    int i = blockIdx.x * 256 + threadIdx.x;
    if (i >= N_NODES) return;
    int r = rp[i] + bsum[blockIdx.x];
    rp[i] = r;
    cursor[i] = r;
    float dv = rsqrtf((float)deg[i] + 1.0f);
    dinv[i] = dv;
    float2 xv = ((const float2*)x)[i];
    xn[i] = make_float2(xv.x * dv, xv.y * dv);
}

// XCD-partitioned scatter, 8 partitions (1.6MB span, one XCD each), int4 loads.
__global__ void __launch_bounds__(256) k_scatter(const int* __restrict__ src,
                                                 const int* __restrict__ dst,
                                                 int* __restrict__ cursor,
                                                 int* __restrict__ csr) {
    int part  = blockIdx.x & 7;
    int chunk = blockIdx.x >> 3;
    int lo = part * PART_SZ, hi = lo + PART_SZ;
    int base = chunk * SC_CHUNK;            // multiple of 2048 -> 16B aligned
    #pragma unroll
    for (int i = 0; i < SC_CHUNK / 1024; ++i) {
        int e4 = base + (i * 256 + threadIdx.x) * 4;
        if (e4 < N_EDGES) {
            int4 d = *(const int4*)(dst + e4);
            int4 s = *(const int4*)(src + e4);
            if (d.x >= lo && d.x < hi) csr[atomicAdd(&cursor[d.x], 1)] = s.x;
            if (d.y >= lo && d.y < hi) csr[atomicAdd(&cursor[d.y], 1)] = s.y;
            if (d.z >= lo && d.z < hi) csr[atomicAdd(&cursor[d.z], 1)] = s.z;
            if (d.w >= lo && d.w < hi) csr[atomicAdd(&cursor[d.w], 1)] = s.w;
        }
    }
}

// ---------- layer 1a: z[v] = xn[v] + sum_{s in N(v)} xn[s]  (fp64 acc, ILP-8) ----------
__global__ void __launch_bounds__(256) k_l1a(const int* __restrict__ rp,
                                             const int* __restrict__ deg,
                                             const int* __restrict__ csr,
                                             const float2* __restrict__ xn,
                                             float2* __restrict__ z) {
    int v = blockIdx.x * 256 + threadIdx.x;
    if (v >= N_NODES) return;
    int beg = rp[v], n = deg[v];
    float2 self = xn[v];
    double ax = self.x, ay = self.y;
    double bx = 0.0,    by = 0.0;
    int j = 0;
    for (; j + 8 <= n; j += 8) {
        int s0 = csr[beg + j],     s1 = csr[beg + j + 1];
        int s2 = csr[beg + j + 2], s3 = csr[beg + j + 3];
        int s4 = csr[beg + j + 4], s5 = csr[beg + j + 5];
        int s6 = csr[beg + j + 6], s7 = csr[beg + j + 7];
        float2 p0 = xn[s0], p1 = xn[s1], p2 = xn[s2], p3 = xn[s3];
        float2 p4 = xn[s4], p5 = xn[s5], p6 = xn[s6], p7 = xn[s7];
        ax += p0.x; ay += p0.y;  bx += p1.x; by += p1.y;
        ax += p2.x; ay += p2.y;  bx += p3.x; by += p3.y;
        ax += p4.x; ay += p4.y;  bx += p5.x; by += p5.y;
        ax += p6.x; ay += p6.y;  bx += p7.x; by += p7.y;
    }
    for (; j < n; ++j) {
        int s = csr[beg + j];
        float2 p = xn[s];
        ax += p.x; ay += p.y;
    }
    z[v] = make_float2((float)(ax + bx), (float)(ay + by));
}

// ---------- layer 1b: g[v] = relu( (z[v]*dinv) @ W1 + b1 ) * dinv ----------
__global__ void __launch_bounds__(256) k_l1b(const float2* __restrict__ z,
                                             const float* __restrict__ dinv,
                                             const float* __restrict__ W1,
                                             const float* __restrict__ b1,
                                             float* __restrict__ g) {
    int gid = blockIdx.x * 256 + threadIdx.x;
    int v = gid >> 6, l = gid & 63;
    if (v >= N_NODES) return;
    float dv = dinv[v];
    float2 zv = z[v];
    float i0 = zv.x * dv;
    float i1 = zv.y * dv;
    float h = fmaf(i0, W1[l], fmaf(i1, W1[64 + l], b1[l]));
    g[v * 64 + l] = fmaxf(h, 0.0f) * dv;    // max idx 12.8M, int is safe
}

// ---------- layer 2 + fc, var nodes only ----------
// float4 row gathers, 4 independent gather streams (16 neighbors in flight),
// fp64 accumulators, shfl_xor fold of the 4 groups at the end.
__global__ void __launch_bounds__(256) k_l2(const int* __restrict__ rp,
                                            const int* __restrict__ deg,
                                            const int* __restrict__ csr,
                                            const float* __restrict__ g,
                                            const float* __restrict__ dinv,
                                            const float* __restrict__ W2,
                                            const float* __restrict__ b2,
                                            const float* __restrict__ Wfc,
                                            const float* __restrict__ bfc,
                                            float* __restrict__ out) {
    __shared__ float A[4][64];
    __shared__ float T[4][64];
    int w = threadIdx.x >> 6, l = threadIdx.x & 63;
    int grp = l >> 4;                      // neighbor slot within a 4-batch
    int q   = l & 15;                      // float4 index within the row
    int v = blockIdx.x * 4 + w;            // grid = N_VAR/4 exactly
    int beg = __builtin_amdgcn_readfirstlane(rp[v]);
    int n   = __builtin_amdgcn_readfirstlane(deg[v]);
    const int* __restrict__ row = csr + beg;
    const float4* __restrict__ g4 = (const float4*)g;

    double aa0 = 0.0, aa1 = 0.0, aa2 = 0.0, aa3 = 0.0;   // stream a
    double ab0 = 0.0, ab1 = 0.0, ab2 = 0.0, ab3 = 0.0;   // stream b
    double ac0 = 0.0, ac1 = 0.0, ac2 = 0.0, ac3 = 0.0;   // stream c
    double ad0 = 0.0, ad1 = 0.0, ad2 = 0.0, ad3 = 0.0;   // stream d
    if (grp == 0) {                        // self loop, group 0 only
        float4 s4 = g4[v * 16 + q];
        aa0 = s4.x; aa1 = s4.y; aa2 = s4.z; aa3 = s4.w;
    }
    int j = 0;
    for (; j + 16 <= n; j += 16) {
        int s0  = row[j],      s1  = row[j + 1],  s2  = row[j + 2],  s3  = row[j + 3];
        int s4i = row[j + 4],  s5  = row[j + 5],  s6  = row[j + 6],  s7  = row[j + 7];
        int s8  = row[j + 8],  s9  = row[j + 9],  s10 = row[j + 10], s11 = row[j + 11];
        int s12 = row[j + 12], s13 = row[j + 13], s14 = row[j + 14], s15 = row[j + 15];
        int ia = (grp == 0) ? s0  : (grp == 1) ? s1  : (grp == 2) ? s2  : s3;
        int ib = (grp == 0) ? s4i : (grp == 1) ? s5  : (grp == 2) ? s6  : s7;
        int ic = (grp == 0) ? s8  : (grp == 1) ? s9  : (grp == 2) ? s10 : s11;
        int id = (grp == 0) ? s12 : (grp == 1) ? s13 : (grp == 2) ? s14 : s15;
        float4 ra = g4[ia * 16 + q];
        float4 rb = g4[ib * 16 + q];
        float4 rc = g4[ic * 16 + q];
        float4 rd = g4[id * 16 + q];
        aa0 += ra.x; aa1 += ra.y; aa2 += ra.z; aa3 += ra.w;
        ab0 += rb.x; ab1 += rb.y; ab2 += rb.z; ab3 += rb.w;
        ac0 += rc.x; ac1 += rc.y; ac2 += rc.z; ac3 += rc.w;
        ad0 += rd.x; ad1 += rd.y; ad2 += rd.z; ad3 += rd.w;
    }
    for (; j + 4 <= n; j += 4) {
        int s0 = row[j], s1 = row[j + 1], s2 = row[j + 2], s3 = row[j + 3];
        int ia = (grp == 0) ? s0 : (grp == 1) ? s1 : (grp == 2) ? s2 : s3;
        float4 ra = g4[ia * 16 + q];
        aa0 += ra.x; aa1 += ra.y; aa2 += ra.z; aa3 += ra.w;
    }
    if (j < n) {                           // remainder 1..3
        int rem = n - j;
        int s0 = row[j];
        int s1 = (rem > 1) ? row[j + 1] : s0;
        int s2 = (rem > 2) ? row[j + 2] : s0;
        int ia = (grp == 0) ? s0 : (grp == 1) ? s1 : s2;
        if (grp < rem) {
            float4 ra = g4[ia * 16 + q];
            aa0 += ra.x; aa1 += ra.y; aa2 += ra.z; aa3 += ra.w;
        }
    }
    double a0 = (aa0 + ab0) + (ac0 + ad0);
    double a1 = (aa1 + ab1) + (ac1 + ad1);
    double a2 = (aa2 + ab2) + (ac2 + ad2);
    double a3 = (aa3 + ab3) + (ac3 + ad3);
    // fold the 4 groups: lanes {q, q+16, q+32, q+48} -> total
    a0 += __shfl_xor(a0, 16); a0 += __shfl_xor(a0, 32);
    a1 += __shfl_xor(a1, 16); a1 += __shfl_xor(a1, 32);
    a2 += __shfl_xor(a2, 16); a2 += __shfl_xor(a2, 32);
    a3 += __shfl_xor(a3, 16); a3 += __shfl_xor(a3, 32);
    float dv = dinv[v];
    if (l < 16) {
        ((float4*)A[w])[q] = make_float4((float)a0 * dv, (float)a1 * dv,
                                         (float)a2 * dv, (float)a3 * dv);
    }
    __syncthreads();
    float t = b2[l];
    #pragma unroll
    for (int jj = 0; jj < 64; ++jj)
        t = fmaf(A[w][jj], W2[jj * 64 + l], t);
    T[w][l] = t;
    __syncthreads();
    float o = bfc[l];
    #pragma unroll
    for (int k = 0; k < 64; ++k)
        o = fmaf(T[w][k], Wfc[k * 64 + l], o);
    out[v * 64 + l] = rintf(fmaxf(o, 0.0f));
}

// ---------------- launch ----------------

extern "C" void kernel_launch(void* const* d_in, const int* in_sizes, int n_in,
                              void* d_out, int out_size, void* d_ws, size_t ws_size,
                              hipStream_t stream) {
    const float* x    = (const float*)d_in[0];
    const int*   ei   = (const int*)  d_in[1];
    const float* W1   = (const float*)d_in[2];
    const float* b1   = (const float*)d_in[3];
    const float* W2   = (const float*)d_in[4];
    const float* b2   = (const float*)d_in[5];
    const float* Wfc  = (const float*)d_in[6];
    const float* bfc  = (const float*)d_in[7];
    float* out = (float*)d_out;

    const int* src = ei;
    const int* dst = ei + N_EDGES;

    // workspace layout (bytes), 16-aligned
    char* ws = (char*)d_ws;
    int*    deg    = (int*)   (ws + 0);          //   800,000
    int*    rp     = (int*)   (ws + 800000);     //   800,000
    int*    cursor = (int*)   (ws + 1600000);    //   800,000
    int*    bsum   = (int*)   (ws + 2400000);    //     4,096
    float*  dinv   = (float*) (ws + 2404096);    //   800,000
    float2* xn     = (float2*)(ws + 3204096);    // 1,600,000
    float2* z      = (float2*)(ws + 4804096);    // 1,600,000
    int*    csr    = (int*)   (ws + 6404096);    // 12,800,000
    float*  g      = (float*) (ws + 19204096);   // 51,200,000 -> total 70.4 MB

    hipMemsetAsync(deg, 0, (size_t)N_NODES * 4, stream);

    k_count  <<<(N_EDGES / 4 + 255) / 256, 256, 0, stream>>>(dst, deg);
    k_scan1  <<<NB_SCAN, 256, 0, stream>>>(deg, rp, bsum);
    k_scan2  <<<1, 1024, 0, stream>>>(bsum);
    k_scan3  <<<NB_SCAN, 256, 0, stream>>>(deg, rp, bsum, cursor, x, dinv, xn);
    k_scatter<<<8 * SC_NCHUNK, 256, 0, stream>>>(src, dst, cursor, csr);

    k_l1a<<<NB_SCAN, 256, 0, stream>>>(rp, deg, csr, xn, z);
    k_l1b<<<(N_NODES * 64 + 255) / 256, 256, 0, stream>>>(z, dinv, W1, b1, g);
    k_l2 <<<N_VAR / 4, 256, 0, stream>>>(rp, deg, csr, g, dinv, W2, b2, Wfc, bfc, out);
}

// Round 9
// 522.129 us; speedup vs baseline: 1.0752x; 1.0752x over previous
//
#include <hip/hip_runtime.h>
#include <math.h>

#define N_NODES 200000
#define N_VAR   112000
#define N_EDGES 3200000
#define NB_SCAN 782           // ceil(200000/256)
#define PART_SZ 25000         // N_NODES / 8 partitions (one XCD each)
#define SC_CHUNK 2048         // edges scanned per scatter block
#define SC_NCHUNK 1563        // ceil(N_EDGES / SC_CHUNK)

// ---------- fold the linear chain: Wc = W2@Wfc, bc = b2@Wfc + bfc (fp64) ----------
__global__ void __launch_bounds__(256) k_setup(const float* __restrict__ W2,
                                               const float* __restrict__ b2,
                                               const float* __restrict__ Wfc,
                                               const float* __restrict__ bfc,
                                               float* __restrict__ Wc,
                                               float* __restrict__ bc) {
    int tid = threadIdx.x;
    #pragma unroll
    for (int k = 0; k < 16; ++k) {
        int e = k * 256 + tid;             // 4096 entries
        int j = e >> 6, l = e & 63;
        double acc = 0.0;
        for (int m = 0; m < 64; ++m)
            acc += (double)W2[j * 64 + m] * (double)Wfc[m * 64 + l];
        Wc[e] = (float)acc;
    }
    if (tid < 64) {
        double acc = (double)bfc[tid];
        for (int m = 0; m < 64; ++m)
            acc += (double)b2[m] * (double)Wfc[m * 64 + tid];
        bc[tid] = (float)acc;
    }
}

// ---------- CSR build ----------

__global__ void k_count(const int* __restrict__ dst, int* __restrict__ deg) {
    int i = blockIdx.x * blockDim.x + threadIdx.x;   // int4 index
    if (i * 4 < N_EDGES) {
        int4 d = ((const int4*)dst)[i];
        atomicAdd(&deg[d.x], 1);
        atomicAdd(&deg[d.y], 1);
        atomicAdd(&deg[d.z], 1);
        atomicAdd(&deg[d.w], 1);
    }
}

__global__ void __launch_bounds__(256) k_scan1(const int* __restrict__ deg,
                                               int* __restrict__ rp,
                                               int* __restrict__ bsum) {
    __shared__ int tmp[256];
    int i = blockIdx.x * 256 + threadIdx.x;
    int v = (i < N_NODES) ? deg[i] : 0;
    tmp[threadIdx.x] = v;
    __syncthreads();
    for (int off = 1; off < 256; off <<= 1) {
        int t = (threadIdx.x >= off) ? tmp[threadIdx.x - off] : 0;
        __syncthreads();
        tmp[threadIdx.x] += t;
        __syncthreads();
    }
    if (i < N_NODES) rp[i] = tmp[threadIdx.x] - v;   // exclusive
    if (threadIdx.x == 255) bsum[blockIdx.x] = tmp[255];
}

__global__ void __launch_bounds__(1024) k_scan2(int* __restrict__ bsum) {
    __shared__ int tmp[1024];
    int v = (threadIdx.x < NB_SCAN) ? bsum[threadIdx.x] : 0;
    tmp[threadIdx.x] = v;
    __syncthreads();
    for (int off = 1; off < 1024; off <<= 1) {
        int t = (threadIdx.x >= off) ? tmp[threadIdx.x - off] : 0;
        __syncthreads();
        tmp[threadIdx.x] += t;
        __syncthreads();
    }
    if (threadIdx.x < NB_SCAN) bsum[threadIdx.x] = tmp[threadIdx.x] - v;
}

// finalize row_ptr, init cursor, compute dinv and xn = x*dinv
__global__ void __launch_bounds__(256) k_scan3(const int* __restrict__ deg,
                                               int* __restrict__ rp,
                                               const int* __restrict__ bsum,
                                               int* __restrict__ cursor,
                                               const float* __restrict__ x,
                                               float* __restrict__ dinv,
                                               float2* __restrict__ xn) {
    int i = blockIdx.x * 256 + threadIdx.x;
    if (i >= N_NODES) return;
    int r = rp[i] + bsum[blockIdx.x];
    rp[i] = r;
    cursor[i] = r;
    float dv = rsqrtf((float)deg[i] + 1.0f);
    dinv[i] = dv;
    float2 xv = ((const float2*)x)[i];
    xn[i] = make_float2(xv.x * dv, xv.y * dv);
}

// XCD-partitioned scatter, 8 partitions (1.6MB span, one XCD each), int4 dst
// loads; src int4 loaded lazily only when the lane owns at least one edge.
__global__ void __launch_bounds__(256) k_scatter(const int* __restrict__ src,
                                                 const int* __restrict__ dst,
                                                 int* __restrict__ cursor,
                                                 int* __restrict__ csr) {
    int part  = blockIdx.x & 7;
    int chunk = blockIdx.x >> 3;
    int lo = part * PART_SZ, hi = lo + PART_SZ;
    int base = chunk * SC_CHUNK;            // multiple of 2048 -> 16B aligned
    #pragma unroll
    for (int i = 0; i < SC_CHUNK / 1024; ++i) {
        int e4 = base + (i * 256 + threadIdx.x) * 4;
        if (e4 < N_EDGES) {
            int4 d = *(const int4*)(dst + e4);
            bool ox = (d.x >= lo && d.x < hi);
            bool oy = (d.y >= lo && d.y < hi);
            bool oz = (d.z >= lo && d.z < hi);
            bool ow = (d.w >= lo && d.w < hi);
            if (ox | oy | oz | ow) {
                int4 s = *(const int4*)(src + e4);
                if (ox) csr[atomicAdd(&cursor[d.x], 1)] = s.x;
                if (oy) csr[atomicAdd(&cursor[d.y], 1)] = s.y;
                if (oz) csr[atomicAdd(&cursor[d.z], 1)] = s.z;
                if (ow) csr[atomicAdd(&cursor[d.w], 1)] = s.w;
            }
        }
    }
}

// ---------- layer 1a: z[v] = xn[v] + sum_{s in N(v)} xn[s]  (fp64 acc, ILP-8) ----------
__global__ void __launch_bounds__(256) k_l1a(const int* __restrict__ rp,
                                             const int* __restrict__ deg,
                                             const int* __restrict__ csr,
                                             const float2* __restrict__ xn,
                                             float2* __restrict__ z) {
    int v = blockIdx.x * 256 + threadIdx.x;
    if (v >= N_NODES) return;
    int beg = rp[v], n = deg[v];
    float2 self = xn[v];
    double ax = self.x, ay = self.y;
    double bx = 0.0,    by = 0.0;
    int j = 0;
    for (; j + 8 <= n; j += 8) {
        int s0 = csr[beg + j],     s1 = csr[beg + j + 1];
        int s2 = csr[beg + j + 2], s3 = csr[beg + j + 3];
        int s4 = csr[beg + j + 4], s5 = csr[beg + j + 5];
        int s6 = csr[beg + j + 6], s7 = csr[beg + j + 7];
        float2 p0 = xn[s0], p1 = xn[s1], p2 = xn[s2], p3 = xn[s3];
        float2 p4 = xn[s4], p5 = xn[s5], p6 = xn[s6], p7 = xn[s7];
        ax += p0.x; ay += p0.y;  bx += p1.x; by += p1.y;
        ax += p2.x; ay += p2.y;  bx += p3.x; by += p3.y;
        ax += p4.x; ay += p4.y;  bx += p5.x; by += p5.y;
        ax += p6.x; ay += p6.y;  bx += p7.x; by += p7.y;
    }
    for (; j < n; ++j) {
        int s = csr[beg + j];
        float2 p = xn[s];
        ax += p.x; ay += p.y;
    }
    z[v] = make_float2((float)(ax + bx), (float)(ay + by));
}

// ---------- layer 1b: g[v] = relu( (z[v]*dinv) @ W1 + b1 ) * dinv ----------
__global__ void __launch_bounds__(256) k_l1b(const float2* __restrict__ z,
                                             const float* __restrict__ dinv,
                                             const float* __restrict__ W1,
                                             const float* __restrict__ b1,
                                             float* __restrict__ g) {
    int gid = blockIdx.x * 256 + threadIdx.x;
    int v = gid >> 6, l = gid & 63;
    if (v >= N_NODES) return;
    float dv = dinv[v];
    float2 zv = z[v];
    float i0 = zv.x * dv;
    float i1 = zv.y * dv;
    float h = fmaf(i0, W1[l], fmaf(i1, W1[64 + l], b1[l]));
    g[v * 64 + l] = fmaxf(h, 0.0f) * dv;    // max idx 12.8M, int is safe
}

// ---------- layer 2 + folded fc, var nodes only ----------
// float4 row gathers (4 streams), fp64 acc, shfl_xor fold; epilogue is ONE
// fp64-accumulated GEMM against LDS-staged Wc (W2@Wfc folded), one barrier.
__global__ void __launch_bounds__(256) k_l2(const int* __restrict__ rp,
                                            const int* __restrict__ deg,
                                            const int* __restrict__ csr,
                                            const float* __restrict__ g,
                                            const float* __restrict__ dinv,
                                            const float* __restrict__ Wc,
                                            const float* __restrict__ bc,
                                            float* __restrict__ out) {
    __shared__ float Wcs[4096];            // 16 KB
    __shared__ float A[4][64];
    int w = threadIdx.x >> 6, l = threadIdx.x & 63;
    #pragma unroll
    for (int k = 0; k < 16; ++k)
        Wcs[k * 256 + threadIdx.x] = Wc[k * 256 + threadIdx.x];

    int grp = l >> 4;                      // neighbor slot within a 4-batch
    int q   = l & 15;                      // float4 index within the row
    int v = blockIdx.x * 4 + w;            // grid = N_VAR/4 exactly
    int beg = __builtin_amdgcn_readfirstlane(rp[v]);
    int n   = __builtin_amdgcn_readfirstlane(deg[v]);
    const int* __restrict__ row = csr + beg;
    const float4* __restrict__ g4 = (const float4*)g;

    double aa0 = 0.0, aa1 = 0.0, aa2 = 0.0, aa3 = 0.0;
    double ab0 = 0.0, ab1 = 0.0, ab2 = 0.0, ab3 = 0.0;
    if (grp == 0) {                        // self loop, group 0 only
        float4 s4 = g4[v * 16 + q];
        aa0 = s4.x; aa1 = s4.y; aa2 = s4.z; aa3 = s4.w;
    }
    int j = 0;
    for (; j + 8 <= n; j += 8) {
        int s0 = row[j],     s1 = row[j + 1], s2 = row[j + 2], s3 = row[j + 3];
        int s4i = row[j + 4], s5 = row[j + 5], s6 = row[j + 6], s7 = row[j + 7];
        int ia = (grp == 0) ? s0  : (grp == 1) ? s1 : (grp == 2) ? s2 : s3;
        int ib = (grp == 0) ? s4i : (grp == 1) ? s5 : (grp == 2) ? s6 : s7;
        float4 ra = g4[ia * 16 + q];
        float4 rb = g4[ib * 16 + q];
        aa0 += ra.x; aa1 += ra.y; aa2 += ra.z; aa3 += ra.w;
        ab0 += rb.x; ab1 += rb.y; ab2 += rb.z; ab3 += rb.w;
    }
    for (; j + 4 <= n; j += 4) {
        int s0 = row[j], s1 = row[j + 1], s2 = row[j + 2], s3 = row[j + 3];
        int ia = (grp == 0) ? s0 : (grp == 1) ? s1 : (grp == 2) ? s2 : s3;
        float4 ra = g4[ia * 16 + q];
        aa0 += ra.x; aa1 += ra.y; aa2 += ra.z; aa3 += ra.w;
    }
    if (j < n) {                           // remainder 1..3
        int rem = n - j;
        int s0 = row[j];
        int s1 = (rem > 1) ? row[j + 1] : s0;
        int s2 = (rem > 2) ? row[j + 2] : s0;
        int ia = (grp == 0) ? s0 : (grp == 1) ? s1 : s2;
        if (grp < rem) {
            float4 ra = g4[ia * 16 + q];
            aa0 += ra.x; aa1 += ra.y; aa2 += ra.z; aa3 += ra.w;
        }
    }
    double a0 = aa0 + ab0, a1 = aa1 + ab1, a2 = aa2 + ab2, a3 = aa3 + ab3;
    a0 += __shfl_xor(a0, 16); a0 += __shfl_xor(a0, 32);
    a1 += __shfl_xor(a1, 16); a1 += __shfl_xor(a1, 32);
    a2 += __shfl_xor(a2, 16); a2 += __shfl_xor(a2, 32);
    a3 += __shfl_xor(a3, 16); a3 += __shfl_xor(a3, 32);
    float dv = dinv[v];
    if (l < 16) {
        ((float4*)A[w])[q] = make_float4((float)a0 * dv, (float)a1 * dv,
                                         (float)a2 * dv, (float)a3 * dv);
    }
    __syncthreads();
    double t = 0.0;
    #pragma unroll
    for (int jj = 0; jj < 64; ++jj)
        t += (double)A[w][jj] * (double)Wcs[jj * 64 + l];
    float o = (float)t + bc[l];
    out[v * 64 + l] = rintf(fmaxf(o, 0.0f));
}

// ---------------- launch ----------------

extern "C" void kernel_launch(void* const* d_in, const int* in_sizes, int n_in,
                              void* d_out, int out_size, void* d_ws, size_t ws_size,
                              hipStream_t stream) {
    const float* x    = (const float*)d_in[0];
    const int*   ei   = (const int*)  d_in[1];
    const float* W1   = (const float*)d_in[2];
    const float* b1   = (const float*)d_in[3];
    const float* W2   = (const float*)d_in[4];
    const float* b2   = (const float*)d_in[5];
    const float* Wfc  = (const float*)d_in[6];
    const float* bfc  = (const float*)d_in[7];
    float* out = (float*)d_out;

    const int* src = ei;
    const int* dst = ei + N_EDGES;

    // workspace layout (bytes), 16-aligned
    char* ws = (char*)d_ws;
    int*    deg    = (int*)   (ws + 0);          //   800,000
    int*    rp     = (int*)   (ws + 800000);     //   800,000
    int*    cursor = (int*)   (ws + 1600000);    //   800,000
    int*    bsum   = (int*)   (ws + 2400000);    //     4,096
    float*  dinv   = (float*) (ws + 2404096);    //   800,000
    float2* xn     = (float2*)(ws + 3204096);    // 1,600,000
    float2* z      = (float2*)(ws + 4804096);    // 1,600,000
    int*    csr    = (int*)   (ws + 6404096);    // 12,800,000
    float*  g      = (float*) (ws + 19204096);   // 51,200,000
    float*  Wc     = (float*) (ws + 70404096);   //    16,384
    float*  bc     = (float*) (ws + 70420480);   //       256  -> total ~70.42 MB

    hipMemsetAsync(deg, 0, (size_t)N_NODES * 4, stream);

    k_setup  <<<1, 256, 0, stream>>>(W2, b2, Wfc, bfc, Wc, bc);
    k_count  <<<(N_EDGES / 4 + 255) / 256, 256, 0, stream>>>(dst, deg);
    k_scan1  <<<NB_SCAN, 256, 0, stream>>>(deg, rp, bsum);
    k_scan2  <<<1, 1024, 0, stream>>>(bsum);
    k_scan3  <<<NB_SCAN, 256, 0, stream>>>(deg, rp, bsum, cursor, x, dinv, xn);
    k_scatter<<<8 * SC_NCHUNK, 256, 0, stream>>>(src, dst, cursor, csr);

    k_l1a<<<NB_SCAN, 256, 0, stream>>>(rp, deg, csr, xn, z);
    k_l1b<<<(N_NODES * 64 + 255) / 256, 256, 0, stream>>>(z, dinv, W1, b1, g);
    k_l2 <<<N_VAR / 4, 256, 0, stream>>>(rp, deg, csr, g, dinv, Wc, bc, out);
}